// Round 6
// baseline (341.234 us; speedup 1.0000x reference)
//
#include <hip/hip_runtime.h>
#include <math.h>

#define NBX 168
#define NBY 480
#define NBL 6
#define PLANE (NBX * NBY)
#define MAPSZ (PLANE * NBL)      /* also = number of (cell,type) groups */
#define EXT 2
#define W 5
#define INV_SQRT2 0.70710678118654752440f
#define INV_CAP 0.0625f

/* ---- spatial tiling (tile = block of cells for the sort) ---- */
#define TW 8                     /* tile width in x-bins  (168/8  = 21) */
#define TH 12                    /* tile height in y-bins (480/12 = 40) */
#define TX (NBX / TW)            /* 21 */
#define TY (NBY / TH)            /* 40 */
#define NT (TX * TY)             /* 840 tiles */
#define CPT (TW * TH)            /* 96 cells per tile */

#define HIST_BLOCKS 128
#define SCAT_BLOCKS 128

/* Branch-free erf, Abramowitz-Stegun 7.1.26 (|err| <= 1.5e-7, |x| <= 2.14 here). */
__device__ __forceinline__ float erf_fast(float x) {
    float ax = fabsf(x);
    float t = __builtin_amdgcn_rcpf(fmaf(0.3275911f, ax, 1.0f));
    float p = fmaf(1.061405429f, t, -1.453152027f);
    p = fmaf(p, t, 1.421413741f);
    p = fmaf(p, t, -0.284496736f);
    p = fmaf(p, t, 0.254829592f);
    p = p * t;
    float e = __expf(-ax * ax);
    float r = fmaf(-p, e, 1.0f);
    return copysignf(r, x);
}

/* 5 axis weights (zeroed for out-of-range bins). b0 = floor(c) = the cell. */
__device__ __forceinline__ void axis_w(float c, int nb, float* g) {
    int b0 = (int)floorf(c);
    float t0 = (float)(b0 - EXT) - c;
    float e[W + 1];
#pragma unroll
    for (int k = 0; k <= W; ++k) e[k] = erf_fast((t0 + (float)k) * INV_SQRT2);
#pragma unroll
    for (int j = 0; j < W; ++j) {
        int b = b0 - EXT + j;
        g[j] = (b >= 0 && b < nb) ? 0.5f * (e[j + 1] - e[j]) : 0.0f;
    }
}

/* Pass A: tile id per instance (ushort) + per-tile histogram. */
__global__ void k_hist(const float* __restrict__ pos, const float* __restrict__ nsx,
                       const float* __restrict__ nsy, const int* __restrict__ idx,
                       int* __restrict__ tileCount, unsigned short* __restrict__ tid16,
                       int n, int Linst) {
    __shared__ int cnt[NT];
    for (int t = threadIdx.x; t < NT; t += blockDim.x) cnt[t] = 0;
    __syncthreads();
    int stride = gridDim.x * blockDim.x;
    for (int i = blockIdx.x * blockDim.x + threadIdx.x; i < Linst; i += stride) {
        int id = idx[i];
        float cx = pos[id] + 0.5f * nsx[id];
        float cy = pos[n + id] + 0.5f * nsy[id];
        int bx = (int)floorf(cx); bx = bx < 0 ? 0 : (bx > NBX - 1 ? NBX - 1 : bx);
        int by = (int)floorf(cy); by = by < 0 ? 0 : (by > NBY - 1 ? NBY - 1 : by);
        int t = (bx / TW) * TY + (by / TH);
        tid16[i] = (unsigned short)t;
        atomicAdd(&cnt[t], 1);
    }
    __syncthreads();
    for (int t = threadIdx.x; t < NT; t += blockDim.x)
        if (cnt[t]) atomicAdd(&tileCount[t], cnt[t]);
}

/* Pass B: exclusive scan over NT tile counts (single block). */
__global__ void k_scan(const int* __restrict__ cnt, int* __restrict__ start,
                       int* __restrict__ cursor) {
    __shared__ int arr[1024];
    int tid = threadIdx.x;
    int v = (tid < NT) ? cnt[tid] : 0;
    arr[tid] = v;
    __syncthreads();
    for (int off = 1; off < 1024; off <<= 1) {
        int u = (tid >= off) ? arr[tid - off] : 0;
        __syncthreads();
        arr[tid] += u;
        __syncthreads();
    }
    if (tid < NT) { int e = arr[tid] - v; start[tid] = e; cursor[tid] = e; }
    if (tid == 0) start[NT] = arr[1023];
}

/* Pass C: tile counting-sort writing PAYLOADS (cx,cy,area,packed id|type). */
__global__ void k_scatter(const float* __restrict__ pos, const float* __restrict__ nsx,
                          const float* __restrict__ nsy, const int* __restrict__ idx,
                          const int* __restrict__ ltyp,
                          const unsigned short* __restrict__ tid16,
                          int* __restrict__ cursor, float4* __restrict__ sorted,
                          int n, int Linst) {
    __shared__ int cnt[NT];
    __shared__ int base[NT];
    int chunk = (Linst + gridDim.x - 1) / gridDim.x;
    int lo = blockIdx.x * chunk;
    int hi = lo + chunk; if (hi > Linst) hi = Linst;
    for (int t = threadIdx.x; t < NT; t += blockDim.x) cnt[t] = 0;
    __syncthreads();
    for (int i = lo + threadIdx.x; i < hi; i += blockDim.x)
        atomicAdd(&cnt[tid16[i]], 1);
    __syncthreads();
    for (int t = threadIdx.x; t < NT; t += blockDim.x) {
        base[t] = cnt[t] ? atomicAdd(&cursor[t], cnt[t]) : 0;
        cnt[t] = 0;
    }
    __syncthreads();
    for (int i = lo + threadIdx.x; i < hi; i += blockDim.x) {
        int id = idx[i];
        int t = (int)tid16[i];
        float sx = nsx[id], sy = nsy[id];
        float cx = pos[id] + 0.5f * sx;
        float cy = pos[n + id] + 0.5f * sy;
        int packed = (id << 3) | (ltyp[id] & 7);
        int r = atomicAdd(&cnt[t], 1);
        sorted[base[t] + r] = make_float4(cx, cy, sx * sy, __int_as_float(packed));
    }
}

__device__ __forceinline__ int local_cell(float4 p, int x0, int y0) {
    int bx = (int)floorf(p.x) - x0;
    int by = (int)floorf(p.y) - y0;
    bx = bx < 0 ? 0 : (bx > TW - 1 ? TW - 1 : bx);
    by = by < 0 ? 0 : (by > TH - 1 ? TH - 1 : by);
    return bx * TH + by;
}

/* Pass C2: per-tile CELL counting-sort -> sorted2 + cellOff[NT*96+1]. */
__global__ void k_subsort(const float4* __restrict__ sorted,
                          const int* __restrict__ tileStart,
                          int* __restrict__ cellOff, float4* __restrict__ sorted2,
                          int Linst) {
    __shared__ int h[CPT];
    __shared__ int s[CPT];
    __shared__ int cur[CPT];
    int t = blockIdx.x, tid = threadIdx.x;
    int lo = tileStart[t], hi = tileStart[t + 1];
    int x0 = (t / TY) * TW, y0 = (t % TY) * TH;
    if (tid < CPT) h[tid] = 0;
    __syncthreads();
    for (int j = lo + tid; j < hi; j += blockDim.x)
        atomicAdd(&h[local_cell(sorted[j], x0, y0)], 1);
    __syncthreads();
    int v = (tid < CPT) ? h[tid] : 0;
    if (tid < CPT) s[tid] = v;
    __syncthreads();
#pragma unroll
    for (int off = 1; off < CPT; off <<= 1) {
        int u = (tid >= off && tid < CPT) ? s[tid - off] : 0;
        __syncthreads();
        if (tid < CPT) s[tid] += u;
        __syncthreads();
    }
    if (tid < CPT) {
        int excl = s[tid] - v;
        cellOff[t * CPT + tid] = lo + excl;
        cur[tid] = excl;
    }
    if (t == 0 && tid == 0) cellOff[NT * CPT] = Linst;
    __syncthreads();
    for (int j = lo + tid; j < hi; j += blockDim.x) {
        float4 p = sorted[j];
        int lc = local_cell(p, x0, y0);
        int r = atomicAdd(&cur[lc], 1);
        sorted2[lo + r] = p;
    }
}

/* group id g = cell*6 + type, cell = bx*NBY + by. Returns [lo,hi) range. */
__device__ __forceinline__ void group_range(int cell, const int* cellOff,
                                            int* lo, int* hi) {
    int bx = cell / NBY, by = cell % NBY;
    int t = (bx / TW) * TY + (by / TH);
    int lc = (bx % TW) * TH + (by % TH);
    int f = t * CPT + lc;
    *lo = cellOff[f];
    *hi = cellOff[f + 1];
}

/* Pass P: per (cell,type) thread — accumulate 5x5 patch in registers,
   write dense k-major patchbuf[k][group]. ZERO atomics. */
__global__ void k_patch(const float4* __restrict__ sorted2,
                        const int* __restrict__ cellOff,
                        float* __restrict__ patchbuf) {
    int g = blockIdx.x * blockDim.x + threadIdx.x;
    if (g >= MAPSZ) return;
    int cell = g / NBL;
    int typ = g - cell * NBL;
    int lo, hi;
    group_range(cell, cellOff, &lo, &hi);
    float acc[W * W];
#pragma unroll
    for (int k = 0; k < W * W; ++k) acc[k] = 0.0f;
    for (int j = lo; j < hi; ++j) {
        float4 p = sorted2[j];
        if ((__float_as_int(p.w) & 7) != typ) continue;
        float gx[W], gy[W];
        axis_w(p.x, NBX, gx);
        axis_w(p.y, NBY, gy);
#pragma unroll
        for (int jx = 0; jx < W; ++jx) {
            float wx = gx[jx] * p.z;
#pragma unroll
            for (int jy = 0; jy < W; ++jy)
                acc[jx * W + jy] = fmaf(wx, gy[jy], acc[jx * W + jy]);
        }
    }
#pragma unroll
    for (int k = 0; k < W * W; ++k)
        patchbuf[(size_t)k * MAPSZ + g] = acc[k];
}

/* Pass D: per bin — pull 25 neighbor-cell patch elements per type,
   fold fracture einsum, write compat. ZERO atomics. */
__global__ void k_dem(const float* __restrict__ patchbuf,
                      const int* __restrict__ frac,
                      float* __restrict__ compat) {
    int bin = blockIdx.x * blockDim.x + threadIdx.x;
    if (bin >= PLANE) return;
    int x = bin / NBY, y = bin - x * NBY;
    float dem[NBL] = {0, 0, 0, 0, 0, 0};
#pragma unroll
    for (int jx = 0; jx < W; ++jx) {
        int cx = x + EXT - jx;
        if (cx < 0 || cx >= NBX) continue;
#pragma unroll
        for (int jy = 0; jy < W; ++jy) {
            int cy = y + EXT - jy;
            if (cy < 0 || cy >= NBY) continue;
            const float* pb = patchbuf + (size_t)(jx * W + jy) * MAPSZ
                              + (size_t)(cx * NBY + cy) * NBL;
#pragma unroll
            for (int l = 0; l < NBL; ++l) dem[l] += pb[l];
        }
    }
#pragma unroll
    for (int t = 0; t < NBL; ++t) {
        float s = 0.0f;
#pragma unroll
        for (int l = 0; l < NBL; ++l) s += dem[l] * (float)frac[t * NBL + l];
        compat[t * PLANE + bin] = s;
    }
}

/* Pass G: per (cell,type) thread — load the group's 25 compat values into
   registers once, then per instance: 12 erfs + register dot -> out[id]. */
__global__ void k_out(const float4* __restrict__ sorted2,
                      const int* __restrict__ cellOff,
                      const float* __restrict__ compat,
                      float* __restrict__ out) {
    int g = blockIdx.x * blockDim.x + threadIdx.x;
    if (g >= MAPSZ) return;
    int cell = g / NBL;
    int typ = g - cell * NBL;
    int lo, hi;
    group_range(cell, cellOff, &lo, &hi);
    if (lo >= hi) return;
    int bx = cell / NBY, by = cell - bx * NBY;
    float cc[W * W];
#pragma unroll
    for (int jx = 0; jx < W; ++jx) {
        int xx = bx - EXT + jx;
        xx = xx < 0 ? 0 : (xx > NBX - 1 ? NBX - 1 : xx);
#pragma unroll
        for (int jy = 0; jy < W; ++jy) {
            int yy = by - EXT + jy;
            yy = yy < 0 ? 0 : (yy > NBY - 1 ? NBY - 1 : yy);
            cc[jx * W + jy] = compat[typ * PLANE + xx * NBY + yy];
        }
    }
    for (int j = lo; j < hi; ++j) {
        float4 p = sorted2[j];
        int packed = __float_as_int(p.w);
        if ((packed & 7) != typ) continue;
        float gx[W], gy[W];
        axis_w(p.x, NBX, gx);
        axis_w(p.y, NBY, gy);
        float sum = 0.0f;
#pragma unroll
        for (int jx = 0; jx < W; ++jx) {
            float row = 0.0f;
#pragma unroll
            for (int jy = 0; jy < W; ++jy)
                row = fmaf(gy[jy], cc[jx * W + jy], row);
            sum = fmaf(gx[jx], row, sum);
        }
        out[packed >> 3] = sum * INV_CAP;
    }
}

/* ---------- fallback (round-1 path) if ws_size is too small ---------- */
__device__ __forceinline__ void axis_frag_fb(float c, int nb, float* g, int* bc) {
    int b0 = (int)floorf(c);
    float t0 = (float)(b0 - EXT) - c;
    float e[W + 1];
#pragma unroll
    for (int k = 0; k <= W; ++k) e[k] = erf_fast((t0 + (float)k) * INV_SQRT2);
#pragma unroll
    for (int j = 0; j < W; ++j) {
        int b = b0 - EXT + j;
        g[j] = (b >= 0 && b < nb) ? 0.5f * (e[j + 1] - e[j]) : 0.0f;
        int bcl = b < 0 ? 0 : b;
        bc[j] = bcl > nb - 1 ? nb - 1 : bcl;
    }
}
__global__ void k_demand_atomic(const float* __restrict__ pos, const float* __restrict__ nsx,
                                const float* __restrict__ nsy, const int* __restrict__ idx,
                                const int* __restrict__ ltyp, float* __restrict__ dem,
                                int n, int Linst) {
    int i = blockIdx.x * blockDim.x + threadIdx.x;
    if (i >= Linst) return;
    int id = idx[i];
    float sx = nsx[id], sy = nsy[id];
    float cx = pos[id] + 0.5f * sx, cy = pos[n + id] + 0.5f * sy;
    float area = sx * sy;
    float gx[W], gy[W]; int bx[W], by[W];
    axis_frag_fb(cx, NBX, gx, bx);
    axis_frag_fb(cy, NBY, gy, by);
    float* plane = dem + ltyp[id] * PLANE;
#pragma unroll
    for (int jx = 0; jx < W; ++jx) {
        float wx = gx[jx] * area;
        if (wx == 0.0f) continue;
        float* row = plane + bx[jx] * NBY;
#pragma unroll
        for (int jy = 0; jy < W; ++jy) {
            float w = wx * gy[jy];
            if (w != 0.0f) atomicAdd(row + by[jy], w);
        }
    }
}
__global__ void k_compat_simple(const float* __restrict__ dem, const int* __restrict__ frac,
                                float* __restrict__ compat) {
    int xy = blockIdx.x * blockDim.x + threadIdx.x;
    if (xy >= PLANE) return;
    float d[NBL];
#pragma unroll
    for (int l = 0; l < NBL; ++l) d[l] = dem[l * PLANE + xy];
#pragma unroll
    for (int t = 0; t < NBL; ++t) {
        float s = 0.0f;
#pragma unroll
        for (int l = 0; l < NBL; ++l) s += d[l] * (float)frac[t * NBL + l];
        compat[t * PLANE + xy] = s;
    }
}
__global__ void k_gather_simple(const float* __restrict__ pos, const float* __restrict__ nsx,
                                const float* __restrict__ nsy, const int* __restrict__ idx,
                                const int* __restrict__ ltyp, const float* __restrict__ compat,
                                float* __restrict__ out, int n, int Linst) {
    int i = blockIdx.x * blockDim.x + threadIdx.x;
    if (i >= Linst) return;
    int id = idx[i];
    float sx = nsx[id], sy = nsy[id];
    float cx = pos[id] + 0.5f * sx, cy = pos[n + id] + 0.5f * sy;
    float gx[W], gy[W]; int bx[W], by[W];
    axis_frag_fb(cx, NBX, gx, bx);
    axis_frag_fb(cy, NBY, gy, by);
    const float* plane = compat + ltyp[id] * PLANE;
    float sum = 0.0f;
#pragma unroll
    for (int jx = 0; jx < W; ++jx) {
        float wx = gx[jx];
        const float* row = plane + bx[jx] * NBY;
#pragma unroll
        for (int jy = 0; jy < W; ++jy) sum += wx * gy[jy] * row[by[jy]];
    }
    out[id] = sum * INV_CAP;
}

extern "C" void kernel_launch(void* const* d_in, const int* in_sizes, int n_in,
                              void* d_out, int out_size, void* d_ws, size_t ws_size,
                              hipStream_t stream) {
    const float* pos  = (const float*)d_in[0];
    const float* nsx  = (const float*)d_in[1];
    const float* nsy  = (const float*)d_in[2];
    const int*   idx  = (const int*)d_in[3];
    const int*   ltyp = (const int*)d_in[4];
    const int*   frac = (const int*)d_in[5];
    int n     = in_sizes[1];
    int Linst = in_sizes[3];
    float* out = (float*)d_out;
    const int bs = 256;

    size_t PBYTES  = (size_t)W * W * MAPSZ * 4;           /* 48.4 MB patchbuf  */
    size_t S2BYTES = (size_t)Linst * 16;                  /* sorted2           */
    size_t CBYTES  = (size_t)MAPSZ * 4;                   /* compat            */
    size_t MBYTES  = (size_t)(3 * NT + 1 + NT * CPT + 1) * 4;
    size_t need = PBYTES + S2BYTES + CBYTES + MBYTES;
    /* aliasing requires sorted(16B*L) + tid16(2B*L) inside patchbuf region */
    bool alias_ok = (size_t)Linst * 18 <= PBYTES;

    if (ws_size >= need && alias_ok) {
        char* base = (char*)d_ws;
        float* patchbuf = (float*)base;                       /* 0 .. PBYTES  */
        float4* sorted  = (float4*)base;                      /* alias, dead before k_patch */
        unsigned short* tid16 = (unsigned short*)(base + (size_t)Linst * 16);
        float4* sorted2 = (float4*)(base + PBYTES);
        float* compat   = (float*)(base + PBYTES + S2BYTES);
        int* tileCount  = (int*)(base + PBYTES + S2BYTES + CBYTES);
        int* tileStart  = tileCount + NT;                     /* NT+1 */
        int* cursor     = tileStart + NT + 1;
        int* cellOff    = cursor + NT;                        /* NT*CPT+1 */

        hipMemsetAsync(tileCount, 0, NT * sizeof(int), stream);
        hipMemsetAsync(out, 0, (size_t)out_size * sizeof(float), stream);

        k_hist<<<HIST_BLOCKS, bs, 0, stream>>>(pos, nsx, nsy, idx, tileCount, tid16, n, Linst);
        k_scan<<<1, 1024, 0, stream>>>(tileCount, tileStart, cursor);
        k_scatter<<<SCAT_BLOCKS, bs, 0, stream>>>(pos, nsx, nsy, idx, ltyp, tid16, cursor,
                                                  sorted, n, Linst);
        k_subsort<<<NT, bs, 0, stream>>>(sorted, tileStart, cellOff, sorted2, Linst);
        k_patch<<<(MAPSZ + bs - 1) / bs, bs, 0, stream>>>(sorted2, cellOff, patchbuf);
        k_dem<<<(PLANE + bs - 1) / bs, bs, 0, stream>>>(patchbuf, frac, compat);
        k_out<<<(MAPSZ + bs - 1) / bs, bs, 0, stream>>>(sorted2, cellOff, compat, out);
    } else {
        float* dem    = (float*)d_ws;
        float* compat = dem + MAPSZ;
        hipMemsetAsync(dem, 0, MAPSZ * sizeof(float), stream);
        hipMemsetAsync(out, 0, (size_t)out_size * sizeof(float), stream);
        k_demand_atomic<<<(Linst + bs - 1) / bs, bs, 0, stream>>>(pos, nsx, nsy, idx, ltyp, dem, n, Linst);
        k_compat_simple<<<(PLANE + bs - 1) / bs, bs, 0, stream>>>(dem, frac, compat);
        k_gather_simple<<<(Linst + bs - 1) / bs, bs, 0, stream>>>(pos, nsx, nsy, idx, ltyp, compat, out, n, Linst);
    }
}

// Round 7
// 202.315 us; speedup vs baseline: 1.6866x; 1.6866x over previous
//
#include <hip/hip_runtime.h>
#include <math.h>

#define NBX 168
#define NBY 480
#define NBL 6
#define PLANE (NBX * NBY)
#define MAPSZ (PLANE * NBL)
#define EXT 2
#define W 5
#define INV_SQRT2 0.70710678118654752440f
#define INV_CAP 0.0625f

/* ---- spatial tiling ---- */
#define TW 8                     /* tile width in x-bins  (168/8  = 21) */
#define TH 12                    /* tile height in y-bins (480/12 = 40) */
#define TX (NBX / TW)            /* 21 */
#define TY (NBY / TH)            /* 40 */
#define NT (TX * TY)             /* 840 tiles */
#define GPT (TW * TH * NBL)      /* 576 (cell,type) groups per tile */
#define LTW (TW + 2 * EXT)       /* 12 */
#define LTH (TH + 2 * EXT)       /* 16 */
#define LTHP 17                  /* padded y stride (bank spread) */
#define TSTRIDE (LTW * LTHP)     /* 204 */
#define SLABP (NBL * TSTRIDE)    /* 1224 floats = 4.9 KB */

#define HIST_BLOCKS 256
#define SCAT_BLOCKS 256

/* Branch-free erf, Abramowitz-Stegun 7.1.26 (|err| <= 1.5e-7, |x| <= 2.14 here). */
__device__ __forceinline__ float erf_fast(float x) {
    float ax = fabsf(x);
    float t = __builtin_amdgcn_rcpf(fmaf(0.3275911f, ax, 1.0f));
    float p = fmaf(1.061405429f, t, -1.453152027f);
    p = fmaf(p, t, 1.421413741f);
    p = fmaf(p, t, -0.284496736f);
    p = fmaf(p, t, 0.254829592f);
    p = p * t;
    float e = __expf(-ax * ax);
    float r = fmaf(-p, e, 1.0f);
    return copysignf(r, x);
}

/* 5 axis weights (zeroed for out-of-range bins). */
__device__ __forceinline__ void axis_w(float c, int nb, float* g) {
    int b0 = (int)floorf(c);
    float t0 = (float)(b0 - EXT) - c;
    float e[W + 1];
#pragma unroll
    for (int k = 0; k <= W; ++k) e[k] = erf_fast((t0 + (float)k) * INV_SQRT2);
#pragma unroll
    for (int j = 0; j < W; ++j) {
        int b = b0 - EXT + j;
        g[j] = (b >= 0 && b < nb) ? 0.5f * (e[j + 1] - e[j]) : 0.0f;
    }
}

/* Pass A: payload build + tile id + per-tile histogram (single gather pass). */
__global__ void k_hist(const float* __restrict__ pos, const float* __restrict__ nsx,
                       const float* __restrict__ nsy, const int* __restrict__ idx,
                       const int* __restrict__ ltyp,
                       int* __restrict__ tileCount, unsigned short* __restrict__ tid16,
                       float4* __restrict__ payload, int n, int Linst) {
    __shared__ int cnt[NT];
    for (int t = threadIdx.x; t < NT; t += blockDim.x) cnt[t] = 0;
    __syncthreads();
    int stride = gridDim.x * blockDim.x;
    for (int i = blockIdx.x * blockDim.x + threadIdx.x; i < Linst; i += stride) {
        int id = idx[i];
        float sx = nsx[id], sy = nsy[id];
        float cx = pos[id] + 0.5f * sx;
        float cy = pos[n + id] + 0.5f * sy;
        int bx = (int)floorf(cx); bx = bx < 0 ? 0 : (bx > NBX - 1 ? NBX - 1 : bx);
        int by = (int)floorf(cy); by = by < 0 ? 0 : (by > NBY - 1 ? NBY - 1 : by);
        int t = (bx / TW) * TY + (by / TH);
        tid16[i] = (unsigned short)t;
        int packed = (id << 3) | (ltyp[id] & 7);
        payload[i] = make_float4(cx, cy, sx * sy, __int_as_float(packed));
        atomicAdd(&cnt[t], 1);
    }
    __syncthreads();
    for (int t = threadIdx.x; t < NT; t += blockDim.x)
        if (cnt[t]) atomicAdd(&tileCount[t], cnt[t]);
}

/* Pass B: exclusive scan over NT tile counts (single block). */
__global__ void k_scan(const int* __restrict__ cnt, int* __restrict__ start,
                       int* __restrict__ cursor) {
    __shared__ int arr[1024];
    int tid = threadIdx.x;
    int v = (tid < NT) ? cnt[tid] : 0;
    arr[tid] = v;
    __syncthreads();
    for (int off = 1; off < 1024; off <<= 1) {
        int u = (tid >= off) ? arr[tid - off] : 0;
        __syncthreads();
        arr[tid] += u;
        __syncthreads();
    }
    if (tid < NT) { int e = arr[tid] - v; start[tid] = e; cursor[tid] = e; }
    if (tid == 0) start[NT] = arr[1023];
}

/* Pass C: tile counting-sort of payloads (reads coalesced payload+tid16). */
__global__ void k_scatter(const float4* __restrict__ payload,
                          const unsigned short* __restrict__ tid16,
                          int* __restrict__ cursor, float4* __restrict__ sorted,
                          int Linst) {
    __shared__ int cnt[NT];
    __shared__ int base[NT];
    int chunk = (Linst + gridDim.x - 1) / gridDim.x;
    int lo = blockIdx.x * chunk;
    int hi = lo + chunk; if (hi > Linst) hi = Linst;
    for (int t = threadIdx.x; t < NT; t += blockDim.x) cnt[t] = 0;
    __syncthreads();
    for (int i = lo + threadIdx.x; i < hi; i += blockDim.x)
        atomicAdd(&cnt[tid16[i]], 1);
    __syncthreads();
    for (int t = threadIdx.x; t < NT; t += blockDim.x) {
        base[t] = cnt[t] ? atomicAdd(&cursor[t], cnt[t]) : 0;
        cnt[t] = 0;
    }
    __syncthreads();
    for (int i = lo + threadIdx.x; i < hi; i += blockDim.x) {
        float4 p = payload[i];
        int t = (int)tid16[i];
        int r = atomicAdd(&cnt[t], 1);
        sorted[base[t] + r] = p;
    }
}

__device__ __forceinline__ int group_key(float4 p, int x0, int y0) {
    int bx = (int)floorf(p.x) - x0;
    int by = (int)floorf(p.y) - y0;
    bx = bx < 0 ? 0 : (bx > TW - 1 ? TW - 1 : bx);
    by = by < 0 ? 0 : (by > TH - 1 ? TH - 1 : by);
    return (bx * TH + by) * NBL + (__float_as_int(p.w) & 7);
}

/* Pass C2: per-tile (cell,type) counting-sort -> sorted2 + groupOff. */
__global__ __launch_bounds__(1024) void k_subsort(const float4* __restrict__ sorted,
                                                  const int* __restrict__ tileStart,
                                                  int* __restrict__ groupOff,
                                                  float4* __restrict__ sorted2,
                                                  int Linst) {
    __shared__ int h[GPT];
    __shared__ int arr[1024];
    __shared__ int cur[GPT];
    int t = blockIdx.x, tid = threadIdx.x;
    int lo = tileStart[t], hi = tileStart[t + 1];
    int x0 = (t / TY) * TW, y0 = (t % TY) * TH;
    if (tid < GPT) h[tid] = 0;
    __syncthreads();
    for (int j = lo + tid; j < hi; j += blockDim.x)
        atomicAdd(&h[group_key(sorted[j], x0, y0)], 1);
    __syncthreads();
    int v = (tid < GPT) ? h[tid] : 0;
    arr[tid] = v;
    __syncthreads();
    for (int off = 1; off < 1024; off <<= 1) {
        int u = (tid >= off) ? arr[tid - off] : 0;
        __syncthreads();
        arr[tid] += u;
        __syncthreads();
    }
    if (tid < GPT) {
        int excl = arr[tid] - v;
        groupOff[t * GPT + tid] = lo + excl;
        cur[tid] = excl;
    }
    if (t == 0 && tid == 0) groupOff[NT * GPT] = Linst;
    __syncthreads();
    for (int j = lo + tid; j < hi; j += blockDim.x) {
        float4 p = sorted[j];
        int key = group_key(p, x0, y0);
        int r = atomicAdd(&cur[key], 1);
        sorted2[lo + r] = p;
    }
}

/* Pass D: one block per tile, one thread per (cell,type) group.
   Register 5x5 patch over the group's ~2 instances, then 25-step
   barrier-phased plain-add merge into the LDS slab (provably race-free:
   within a step, distinct groups hit distinct bins). ZERO atomics. */
__global__ __launch_bounds__(GPT) void k_demand2(const float4* __restrict__ sorted2,
                                                 const int* __restrict__ groupOff,
                                                 float* __restrict__ slabs) {
    __shared__ float slab[SLABP];
    int t = blockIdx.x, tid = threadIdx.x;
    for (int s = tid; s < SLABP; s += GPT) slab[s] = 0.0f;
    int G = t * GPT + tid;
    int lo = groupOff[G], hi = groupOff[G + 1];
    int typ = tid % NBL, lc = tid / NBL;
    int lx = lc / TH, ly = lc % TH;
    float acc[W * W];
#pragma unroll
    for (int k = 0; k < W * W; ++k) acc[k] = 0.0f;
    for (int j = lo; j < hi; ++j) {
        float4 p = sorted2[j];
        float gx[W], gy[W];
        axis_w(p.x, NBX, gx);
        axis_w(p.y, NBY, gy);
#pragma unroll
        for (int jx = 0; jx < W; ++jx) {
            float wx = gx[jx] * p.z;
#pragma unroll
            for (int jy = 0; jy < W; ++jy)
                acc[jx * W + jy] = fmaf(wx, gy[jy], acc[jx * W + jy]);
        }
    }
    bool active = hi > lo;
    int base = typ * TSTRIDE + lx * LTHP + ly;
#pragma unroll
    for (int jx = 0; jx < W; ++jx) {
#pragma unroll
        for (int jy = 0; jy < W; ++jy) {
            __syncthreads();
            if (active) slab[base + jx * LTHP + jy] += acc[jx * W + jy];
        }
    }
    __syncthreads();
    float* o = slabs + (size_t)t * SLABP;
    for (int s = tid; s < SLABP; s += GPT) o[s] = slab[s];
}

/* Pass E: assemble demand from overlapping padded slabs + fracture einsum. */
__global__ void k_compat(const float* __restrict__ slabs, const int* __restrict__ frac,
                         float* __restrict__ compat) {
    int xy = blockIdx.x * blockDim.x + threadIdx.x;
    if (xy >= PLANE) return;
    int x = xy / NBY, y = xy % NBY;
    int tx = x / TW, xm = x % TW;
    int ty = y / TH, ym = y % TH;
    float d[NBL] = {0, 0, 0, 0, 0, 0};
    int ax0 = (xm < EXT && tx > 0) ? tx - 1 : tx;
    int ax1 = (xm >= TW - EXT && tx < TX - 1) ? tx + 1 : tx;
    int ay0 = (ym < EXT && ty > 0) ? ty - 1 : ty;
    int ay1 = (ym >= TH - EXT && ty < TY - 1) ? ty + 1 : ty;
    for (int ax = ax0; ax <= ax1; ++ax)
        for (int ay = ay0; ay <= ay1; ++ay) {
            int lx = x - (ax * TW - EXT);
            int ly = y - (ay * TH - EXT);
            const float* sl = slabs + (size_t)(ax * TY + ay) * SLABP + lx * LTHP + ly;
#pragma unroll
            for (int l = 0; l < NBL; ++l) d[l] += sl[l * TSTRIDE];
        }
#pragma unroll
    for (int t = 0; t < NBL; ++t) {
        float s = 0.0f;
#pragma unroll
        for (int l = 0; l < NBL; ++l) s += d[l] * (float)frac[t * NBL + l];
        compat[t * PLANE + xy] = s;
    }
}

/* Pass F: per-tile gather, one thread per INSTANCE (dense lanes):
   coalesced payload read, 12 dense erfs, 25 cheap LDS reads, dot, store. */
__global__ void k_out2(const float4* __restrict__ sorted2,
                       const int* __restrict__ tileStart,
                       const float* __restrict__ compat,
                       float* __restrict__ out) {
    __shared__ float cc[SLABP];
    int t = blockIdx.x;
    int x0 = (t / TY) * TW, y0 = (t % TY) * TH;
    for (int s = threadIdx.x; s < SLABP; s += blockDim.x) {
        int l = s / TSTRIDE, r = s % TSTRIDE;
        int gx = x0 - EXT + r / LTHP, gy = y0 - EXT + r % LTHP;
        cc[s] = (gx >= 0 && gx < NBX && gy >= 0 && gy < NBY)
                    ? compat[l * PLANE + gx * NBY + gy] : 0.0f;
    }
    __syncthreads();
    int lo = tileStart[t], hi = tileStart[t + 1];
    for (int j = lo + threadIdx.x; j < hi; j += blockDim.x) {
        float4 p = sorted2[j];
        int packed = __float_as_int(p.w);
        int typ = packed & 7;
        float gxw[W], gyw[W];
        axis_w(p.x, NBX, gxw);
        axis_w(p.y, NBY, gyw);
        int lx = (int)floorf(p.x) - x0, ly = (int)floorf(p.y) - y0;
        lx = lx < 0 ? 0 : (lx > TW - 1 ? TW - 1 : lx);
        ly = ly < 0 ? 0 : (ly > TH - 1 ? TH - 1 : ly);
        int base = typ * TSTRIDE + lx * LTHP + ly;
        float sum = 0.0f;
#pragma unroll
        for (int jx = 0; jx < W; ++jx) {
            float row = 0.0f;
#pragma unroll
            for (int jy = 0; jy < W; ++jy)
                row = fmaf(gyw[jy], cc[base + jx * LTHP + jy], row);
            sum = fmaf(gxw[jx], row, sum);
        }
        out[packed >> 3] = sum * INV_CAP;
    }
}

/* ---------- fallback (atomic path) if ws_size is too small ---------- */
__device__ __forceinline__ void axis_frag_fb(float c, int nb, float* g, int* bc) {
    int b0 = (int)floorf(c);
    float t0 = (float)(b0 - EXT) - c;
    float e[W + 1];
#pragma unroll
    for (int k = 0; k <= W; ++k) e[k] = erf_fast((t0 + (float)k) * INV_SQRT2);
#pragma unroll
    for (int j = 0; j < W; ++j) {
        int b = b0 - EXT + j;
        g[j] = (b >= 0 && b < nb) ? 0.5f * (e[j + 1] - e[j]) : 0.0f;
        int bcl = b < 0 ? 0 : b;
        bc[j] = bcl > nb - 1 ? nb - 1 : bcl;
    }
}
__global__ void k_demand_atomic(const float* __restrict__ pos, const float* __restrict__ nsx,
                                const float* __restrict__ nsy, const int* __restrict__ idx,
                                const int* __restrict__ ltyp, float* __restrict__ dem,
                                int n, int Linst) {
    int i = blockIdx.x * blockDim.x + threadIdx.x;
    if (i >= Linst) return;
    int id = idx[i];
    float sx = nsx[id], sy = nsy[id];
    float cx = pos[id] + 0.5f * sx, cy = pos[n + id] + 0.5f * sy;
    float area = sx * sy;
    float gx[W], gy[W]; int bx[W], by[W];
    axis_frag_fb(cx, NBX, gx, bx);
    axis_frag_fb(cy, NBY, gy, by);
    float* plane = dem + ltyp[id] * PLANE;
#pragma unroll
    for (int jx = 0; jx < W; ++jx) {
        float wx = gx[jx] * area;
        if (wx == 0.0f) continue;
        float* row = plane + bx[jx] * NBY;
#pragma unroll
        for (int jy = 0; jy < W; ++jy) {
            float w = wx * gy[jy];
            if (w != 0.0f) atomicAdd(row + by[jy], w);
        }
    }
}
__global__ void k_compat_simple(const float* __restrict__ dem, const int* __restrict__ frac,
                                float* __restrict__ compat) {
    int xy = blockIdx.x * blockDim.x + threadIdx.x;
    if (xy >= PLANE) return;
    float d[NBL];
#pragma unroll
    for (int l = 0; l < NBL; ++l) d[l] = dem[l * PLANE + xy];
#pragma unroll
    for (int t = 0; t < NBL; ++t) {
        float s = 0.0f;
#pragma unroll
        for (int l = 0; l < NBL; ++l) s += d[l] * (float)frac[t * NBL + l];
        compat[t * PLANE + xy] = s;
    }
}
__global__ void k_gather_simple(const float* __restrict__ pos, const float* __restrict__ nsx,
                                const float* __restrict__ nsy, const int* __restrict__ idx,
                                const int* __restrict__ ltyp, const float* __restrict__ compat,
                                float* __restrict__ out, int n, int Linst) {
    int i = blockIdx.x * blockDim.x + threadIdx.x;
    if (i >= Linst) return;
    int id = idx[i];
    float sx = nsx[id], sy = nsy[id];
    float cx = pos[id] + 0.5f * sx, cy = pos[n + id] + 0.5f * sy;
    float gx[W], gy[W]; int bx[W], by[W];
    axis_frag_fb(cx, NBX, gx, bx);
    axis_frag_fb(cy, NBY, gy, by);
    const float* plane = compat + ltyp[id] * PLANE;
    float sum = 0.0f;
#pragma unroll
    for (int jx = 0; jx < W; ++jx) {
        float wx = gx[jx];
        const float* row = plane + bx[jx] * NBY;
#pragma unroll
        for (int jy = 0; jy < W; ++jy) sum += wx * gy[jy] * row[by[jy]];
    }
    out[id] = sum * INV_CAP;
}

extern "C" void kernel_launch(void* const* d_in, const int* in_sizes, int n_in,
                              void* d_out, int out_size, void* d_ws, size_t ws_size,
                              hipStream_t stream) {
    const float* pos  = (const float*)d_in[0];
    const float* nsx  = (const float*)d_in[1];
    const float* nsy  = (const float*)d_in[2];
    const int*   idx  = (const int*)d_in[3];
    const int*   ltyp = (const int*)d_in[4];
    const int*   frac = (const int*)d_in[5];
    int n     = in_sizes[1];
    int Linst = in_sizes[3];
    float* out = (float*)d_out;
    const int bs = 256;

    size_t S16 = (size_t)Linst * 16;
    size_t need = 2 * S16                                  /* sorted + payload/sorted2 */
                + (size_t)NT * SLABP * 4                   /* slabs    4.1 MB  */
                + (size_t)MAPSZ * 4                        /* compat   1.9 MB  */
                + (size_t)(3 * NT + 1 + NT * GPT + 1) * 4  /* counters+groupOff */
                + (size_t)Linst * 2;                       /* tid16    2 MB    */

    if (ws_size >= need) {
        char* base = (char*)d_ws;
        float4* sorted  = (float4*)base;
        float4* payload = (float4*)(base + S16);  /* dead after k_scatter */
        float4* sorted2 = payload;                /* reborn in k_subsort  */
        float* slabs    = (float*)(base + 2 * S16);
        float* compat   = slabs + (size_t)NT * SLABP;
        int* tileCount  = (int*)(compat + MAPSZ);
        int* tileStart  = tileCount + NT;                 /* NT+1 */
        int* cursor     = tileStart + NT + 1;
        int* groupOff   = cursor + NT;                    /* NT*GPT+1 */
        unsigned short* tid16 = (unsigned short*)(groupOff + NT * GPT + 1);

        hipMemsetAsync(tileCount, 0, NT * sizeof(int), stream);
        hipMemsetAsync(out, 0, (size_t)out_size * sizeof(float), stream);

        k_hist<<<HIST_BLOCKS, bs, 0, stream>>>(pos, nsx, nsy, idx, ltyp,
                                               tileCount, tid16, payload, n, Linst);
        k_scan<<<1, 1024, 0, stream>>>(tileCount, tileStart, cursor);
        k_scatter<<<SCAT_BLOCKS, bs, 0, stream>>>(payload, tid16, cursor, sorted, Linst);
        k_subsort<<<NT, 1024, 0, stream>>>(sorted, tileStart, groupOff, sorted2, Linst);
        k_demand2<<<NT, GPT, 0, stream>>>(sorted2, groupOff, slabs);
        k_compat<<<(PLANE + bs - 1) / bs, bs, 0, stream>>>(slabs, frac, compat);
        k_out2<<<NT, bs, 0, stream>>>(sorted2, tileStart, compat, out);
    } else {
        float* dem    = (float*)d_ws;
        float* compat = dem + MAPSZ;
        hipMemsetAsync(dem, 0, MAPSZ * sizeof(float), stream);
        hipMemsetAsync(out, 0, (size_t)out_size * sizeof(float), stream);
        k_demand_atomic<<<(Linst + bs - 1) / bs, bs, 0, stream>>>(pos, nsx, nsy, idx, ltyp, dem, n, Linst);
        k_compat_simple<<<(PLANE + bs - 1) / bs, bs, 0, stream>>>(dem, frac, compat);
        k_gather_simple<<<(Linst + bs - 1) / bs, bs, 0, stream>>>(pos, nsx, nsy, idx, ltyp, compat, out, n, Linst);
    }
}